// Round 1
// baseline (1152.350 us; speedup 1.0000x reference)
//
#include <hip/hip_runtime.h>

// SelfAttention (Galerkin linear attention) on gfx950.
// Pipeline: [memset scores] -> pos_kernel (posT[c][n]) -> kv_scores (K,V proj +
// per-head LN + S=K^T V via MFMA + atomic reduce) -> w2_kernel (fold S into Wq)
// -> out_kernel ((x+pos) @ W2^T + b2, final LN, transposed NCHW store).
// All GEMMs: bf16 MFMA 16x16x32, fp32 accumulate. Q never materialized.

typedef float floatx4 __attribute__((ext_vector_type(4)));
typedef __bf16 bf16x8 __attribute__((ext_vector_type(8)));

#define LDK 72  // padded LDS k-stride in bf16 elems (144 B = 36 dwords -> <=2-way bank conflict)

static __device__ __forceinline__ unsigned short f2bf(float f) {
  unsigned int u = __builtin_bit_cast(unsigned int, f);
  u += 0x7FFFu + ((u >> 16) & 1u);  // round-to-nearest-even
  return (unsigned short)(u >> 16);
}

static __device__ __forceinline__ floatx4 mfma16(bf16x8 a, bf16x8 b, floatx4 c) {
  return __builtin_amdgcn_mfma_f32_16x16x32_bf16(a, b, c, 0, 0, 0);
}

static __device__ __forceinline__ bf16x8 ldsfrag(const unsigned short* p) {
  return *(const bf16x8*)p;
}

// ---------------------------------------------------------------------------
// posT[k][n], k in [0,256), n in [0,16384): DETR sine embedding, transposed so
// staging reads are n-contiguous (same pattern as x[b][k][n]).
__global__ __launch_bounds__(256) void pos_kernel(float* __restrict__ posT) {
  const int idx = (int)blockIdx.x * 256 + (int)threadIdx.x;  // 256*16384 total
  const int k = idx >> 14;
  const int n = idx & 16383;
  const int i = n >> 7, j = n & 127;
  const float sc = 6.283185307179586f / (128.0f + 1e-6f);
  const float coord = ((k < 128) ? (float)(i + 1) : (float)(j + 1)) * sc;
  const int kk = k & 127;
  const float e = (float)(kk >> 1) * (1.0f / 64.0f);        // 2*floor(kk/2)/128
  const float inv = exp2f(-13.287712379549449f * e);        // 10000^-e
  const float arg = coord * inv;
  posT[idx] = (kk & 1) ? cosf(arg) : sinf(arg);
}

// ---------------------------------------------------------------------------
// Per block: batch b, head-variant hv (heads hv*4..hv*4+3 => out cols hv*128..+128
// of both Wk and Wv). Grid-strides over 8 chunks of 64 rows. For each chunk:
// GEMM K,V tiles -> bias -> per-head LN (shuffle over 32 cols) -> bf16 K^T/V^T
// into LDS -> MFMA S += K^T V (wave w owns head hv*4+w) -> atomicAdd at end.
__global__ __launch_bounds__(256) void kv_scores_kernel(
    const float* __restrict__ x, const float* __restrict__ posT,
    const float* __restrict__ Wk, const float* __restrict__ bk,
    const float* __restrict__ Wv, const float* __restrict__ bv,
    const float* __restrict__ gK, const float* __restrict__ bKp,
    const float* __restrict__ gV, const float* __restrict__ bVp,
    float* __restrict__ scores) {
  __shared__ unsigned short smem[2 * 64 * LDK + 2 * 128 * LDK];  // 55296 B
  unsigned short* Aqk = smem;                 // [64][LDK]  x+pos tile
  unsigned short* Ax  = smem + 64 * LDK;      // [64][LDK]  x tile
  unsigned short* Bk  = smem + 2 * 64 * LDK;  // [128][LDK] Wk rows
  unsigned short* Bv  = Bk + 128 * LDK;       // [128][LDK] Wv rows
  unsigned short* KT  = Bk;                   // reuse: [128 cols][LDK rows]
  unsigned short* VT  = Bv;

  const int tid = (int)threadIdx.x;
  const int lane = tid & 63;
  const int wv = tid >> 6;        // wave 0..3
  const int l15 = lane & 15;
  const int l4 = lane >> 4;
  const int hv = (int)blockIdx.y; // head variant 0..1
  const int b = (int)blockIdx.z;
  const int gx = (int)blockIdx.x; // 0..31
  const int oc0 = hv * 128;
  const float* xb = x + (size_t)b * 256 * 16384;

  floatx4 sacc[2][2] = {};  // S partial for head hv*4+wv, 2x2 tiles of 16x16

  for (int it = 0; it < 8; ++it) {
    const int n0 = (gx * 8 + it) * 64;
    floatx4 acck[8] = {};
    floatx4 accv[8] = {};
    for (int k0 = 0; k0 < 256; k0 += 64) {
      // ---- stage A tiles (transpose: 4 k-consecutive per thread -> b64 write)
      {
        const int n_l = tid & 63;
        const int kg = tid >> 6;
#pragma unroll
        for (int p = 0; p < 4; ++p) {
          const int kb = kg * 4 + p * 16;
          ushort4 uq, ux;
#pragma unroll
          for (int i2 = 0; i2 < 4; ++i2) {
            const int kk = k0 + kb + i2;
            const float xvv = xb[kk * 16384 + n0 + n_l];
            const float pvv = posT[kk * 16384 + n0 + n_l];
            ((unsigned short*)&uq)[i2] = f2bf(xvv + pvv);
            ((unsigned short*)&ux)[i2] = f2bf(xvv);
          }
          *(ushort4*)(Aqk + n_l * LDK + kb) = uq;
          *(ushort4*)(Ax + n_l * LDK + kb) = ux;
        }
      }
      // ---- stage B tiles (weights are [oc][k] = B^T, k-contiguous)
      for (int idx = tid; idx < 128 * 16; idx += 256) {
        const int och = idx >> 4;
        const int q4 = idx & 15;
        const float4 wk4 = *(const float4*)(Wk + (oc0 + och) * 256 + k0 + q4 * 4);
        const float4 wv4 = *(const float4*)(Wv + (oc0 + och) * 256 + k0 + q4 * 4);
        ushort4 uk, uv;
        uk.x = f2bf(wk4.x); uk.y = f2bf(wk4.y); uk.z = f2bf(wk4.z); uk.w = f2bf(wk4.w);
        uv.x = f2bf(wv4.x); uv.y = f2bf(wv4.y); uv.z = f2bf(wv4.z); uv.w = f2bf(wv4.w);
        *(ushort4*)(Bk + och * LDK + q4 * 4) = uk;
        *(ushort4*)(Bv + och * LDK + q4 * 4) = uv;
      }
      __syncthreads();
      // ---- MFMA: wave wv owns rows [wv*16, wv*16+16), all 256 cols (128 K + 128 V)
      const int arow = (wv * 16 + l15) * LDK;
#pragma unroll
      for (int ks = 0; ks < 2; ++ks) {
        const int ko = ks * 32 + l4 * 8;
        const bf16x8 aq = ldsfrag(Aqk + arow + ko);
        const bf16x8 ax = ldsfrag(Ax + arow + ko);
#pragma unroll
        for (int t = 0; t < 8; ++t) {
          const bf16x8 bfk = ldsfrag(Bk + (t * 16 + l15) * LDK + ko);
          acck[t] = mfma16(aq, bfk, acck[t]);
          const bf16x8 bfv = ldsfrag(Bv + (t * 16 + l15) * LDK + ko);
          accv[t] = mfma16(ax, bfv, accv[t]);
        }
      }
      __syncthreads();
    }
    // ---- bias
#pragma unroll
    for (int t = 0; t < 8; ++t) {
      const int och = oc0 + t * 16 + l15;
      const float bkv = bk[och];
      const float bvv = bv[och];
#pragma unroll
      for (int r = 0; r < 4; ++r) { acck[t][r] += bkv; accv[t][r] += bvv; }
    }
    // ---- per-head LN over 32 cols (tiles 2p,2p+1; reduce over 16 lane-cols)
#pragma unroll
    for (int p = 0; p < 4; ++p) {
      const int h = hv * 4 + p;
      const float gk0 = gK[h * 32 + l15], gk1 = gK[h * 32 + 16 + l15];
      const float ok0 = bKp[h * 32 + l15], ok1 = bKp[h * 32 + 16 + l15];
      const float gv0 = gV[h * 32 + l15], gv1 = gV[h * 32 + 16 + l15];
      const float ov0 = bVp[h * 32 + l15], ov1 = bVp[h * 32 + 16 + l15];
#pragma unroll
      for (int r = 0; r < 4; ++r) {
        {
          const float a0 = acck[2 * p][r], a1 = acck[2 * p + 1][r];
          float s = a0 + a1, q = a0 * a0 + a1 * a1;
#pragma unroll
          for (int m = 1; m < 16; m <<= 1) { s += __shfl_xor(s, m); q += __shfl_xor(q, m); }
          const float mu = s * (1.0f / 32.0f);
          const float rstd = rsqrtf(q * (1.0f / 32.0f) - mu * mu + 1e-5f);
          acck[2 * p][r] = (a0 - mu) * rstd * gk0 + ok0;
          acck[2 * p + 1][r] = (a1 - mu) * rstd * gk1 + ok1;
        }
        {
          const float a0 = accv[2 * p][r], a1 = accv[2 * p + 1][r];
          float s = a0 + a1, q = a0 * a0 + a1 * a1;
#pragma unroll
          for (int m = 1; m < 16; m <<= 1) { s += __shfl_xor(s, m); q += __shfl_xor(q, m); }
          const float mu = s * (1.0f / 32.0f);
          const float rstd = rsqrtf(q * (1.0f / 32.0f) - mu * mu + 1e-5f);
          accv[2 * p][r] = (a0 - mu) * rstd * gv0 + ov0;
          accv[2 * p + 1][r] = (a1 - mu) * rstd * gv1 + ov1;
        }
      }
    }
    // ---- write K^T / V^T to LDS ([col][row], rows reg-packed -> b64)
#pragma unroll
    for (int t = 0; t < 8; ++t) {
      const int c = t * 16 + l15;
      const int ro = wv * 16 + l4 * 4;
      ushort4 uk, uv;
      uk.x = f2bf(acck[t][0]); uk.y = f2bf(acck[t][1]); uk.z = f2bf(acck[t][2]); uk.w = f2bf(acck[t][3]);
      uv.x = f2bf(accv[t][0]); uv.y = f2bf(accv[t][1]); uv.z = f2bf(accv[t][2]); uv.w = f2bf(accv[t][3]);
      *(ushort4*)(KT + c * LDK + ro) = uk;
      *(ushort4*)(VT + c * LDK + ro) = uv;
    }
    __syncthreads();
    // ---- S += K^T V over these 64 rows; wave wv's head cols [wv*32, wv*32+32)
#pragma unroll
    for (int ks = 0; ks < 2; ++ks) {
      const int ko = ks * 32 + l4 * 8;
      const bf16x8 a0 = ldsfrag(KT + (wv * 32 + l15) * LDK + ko);
      const bf16x8 a1 = ldsfrag(KT + (wv * 32 + 16 + l15) * LDK + ko);
      const bf16x8 b0 = ldsfrag(VT + (wv * 32 + l15) * LDK + ko);
      const bf16x8 b1 = ldsfrag(VT + (wv * 32 + 16 + l15) * LDK + ko);
      sacc[0][0] = mfma16(a0, b0, sacc[0][0]);
      sacc[0][1] = mfma16(a0, b1, sacc[0][1]);
      sacc[1][0] = mfma16(a1, b0, sacc[1][0]);
      sacc[1][1] = mfma16(a1, b1, sacc[1][1]);
    }
    __syncthreads();  // before next iteration's B-staging overwrites KT/VT
  }
  // ---- reduce to global scores (raw sum; /n applied in w2_kernel)
  const int h = hv * 4 + wv;
#pragma unroll
  for (int di = 0; di < 2; ++di)
#pragma unroll
    for (int ej = 0; ej < 2; ++ej)
#pragma unroll
      for (int r = 0; r < 4; ++r) {
        const int d = di * 16 + l4 * 4 + r;
        const int e = ej * 16 + l15;
        atomicAdd(scores + ((b * 8 + h) * 32 + d) * 32 + e, sacc[di][ej][r]);
      }
}

// ---------------------------------------------------------------------------
// W2[b][h*32+e][r] = sum_d Wq[h*32+d][r] * S[b][h][d][e] / n  (bf16 out)
// b2[b][h*32+e]    = sum_d bq[h*32+d]    * S[b][h][d][e] / n
__global__ __launch_bounds__(256) void w2_kernel(
    const float* __restrict__ Wq, const float* __restrict__ bq,
    const float* __restrict__ scores, unsigned short* __restrict__ W2,
    float* __restrict__ b2) {
  const int b = (int)blockIdx.y;
  const int row = (int)blockIdx.x;  // 0..255: W2 row; 256: b2
  const int t = (int)threadIdx.x;
  const float inv_n = 1.0f / 16384.0f;
  if (row < 256) {
    const int h = row >> 5, e = row & 31;
    float s = 0.0f;
#pragma unroll
    for (int d = 0; d < 32; ++d)
      s += Wq[(h * 32 + d) * 256 + t] * scores[((b * 8 + h) * 32 + d) * 32 + e];
    W2[(size_t)b * 65536 + row * 256 + t] = f2bf(s * inv_n);
  } else {
    const int h = t >> 5, e = t & 31;
    float s = 0.0f;
#pragma unroll
    for (int d = 0; d < 32; ++d)
      s += bq[h * 32 + d] * scores[((b * 8 + h) * 32 + d) * 32 + e];
    b2[b * 256 + t] = s * inv_n;
  }
}

// ---------------------------------------------------------------------------
// out_pre = (x+pos) @ W2[b]^T + b2; doubled (out+out); LN over 256; store NCHW.
__global__ __launch_bounds__(256) void out_kernel(
    const float* __restrict__ x, const float* __restrict__ posT,
    const unsigned short* __restrict__ W2, const float* __restrict__ b2,
    const float* __restrict__ g_ln, const float* __restrict__ b_ln,
    float* __restrict__ out) {
  __shared__ unsigned short smem[64 * LDK + 256 * LDK];  // 46080 B
  unsigned short* A = smem;
  unsigned short* Bw = smem + 64 * LDK;
  const int tid = (int)threadIdx.x;
  const int lane = tid & 63;
  const int wv = tid >> 6;
  const int l15 = lane & 15;
  const int l4 = lane >> 4;
  const int b = (int)blockIdx.y;
  const int n0 = (int)blockIdx.x * 64;
  const float* xb = x + (size_t)b * 256 * 16384;
  const unsigned short* W2b = W2 + (size_t)b * 65536;
  floatx4 acc[16] = {};
  for (int k0 = 0; k0 < 256; k0 += 64) {
    {
      const int n_l = tid & 63;
      const int kg = tid >> 6;
#pragma unroll
      for (int p = 0; p < 4; ++p) {
        const int kb = kg * 4 + p * 16;
        ushort4 uq;
#pragma unroll
        for (int i2 = 0; i2 < 4; ++i2) {
          const int kk = k0 + kb + i2;
          const float xvv = xb[kk * 16384 + n0 + n_l];
          const float pvv = posT[kk * 16384 + n0 + n_l];
          ((unsigned short*)&uq)[i2] = f2bf(xvv + pvv);
        }
        *(ushort4*)(A + n_l * LDK + kb) = uq;
      }
    }
    for (int idx = tid; idx < 256 * 16; idx += 256) {
      const int och = idx >> 4;
      const int q4 = idx & 15;
      const ushort4 u = *(const ushort4*)(W2b + och * 256 + k0 + q4 * 4);
      *(ushort4*)(Bw + och * LDK + q4 * 4) = u;
    }
    __syncthreads();
    const int arow = (wv * 16 + l15) * LDK;
#pragma unroll
    for (int ks = 0; ks < 2; ++ks) {
      const int ko = ks * 32 + l4 * 8;
      const bf16x8 a = ldsfrag(A + arow + ko);
#pragma unroll
      for (int t = 0; t < 16; ++t) {
        const bf16x8 bb = ldsfrag(Bw + (t * 16 + l15) * LDK + ko);
        acc[t] = mfma16(a, bb, acc[t]);
      }
    }
    __syncthreads();
  }
  // epilogue: bias, double (out+out), LN over 256 cols, transposed store
  float vals[16][4];
#pragma unroll
  for (int t = 0; t < 16; ++t) {
    const float b2v = b2[b * 256 + t * 16 + l15];
#pragma unroll
    for (int r = 0; r < 4; ++r) vals[t][r] = 2.0f * (acc[t][r] + b2v);
  }
  float mean[4], rstd[4];
#pragma unroll
  for (int r = 0; r < 4; ++r) {
    float s = 0.0f, q = 0.0f;
#pragma unroll
    for (int t = 0; t < 16; ++t) { const float v2 = vals[t][r]; s += v2; q += v2 * v2; }
#pragma unroll
    for (int m = 1; m < 16; m <<= 1) { s += __shfl_xor(s, m); q += __shfl_xor(q, m); }
    const float mu = s * (1.0f / 256.0f);
    mean[r] = mu;
    rstd[r] = rsqrtf(q * (1.0f / 256.0f) - mu * mu + 1e-5f);
  }
#pragma unroll
  for (int t = 0; t < 16; ++t) {
    const int c = t * 16 + l15;
    const float g = g_ln[c], be = b_ln[c];
    float4 o;
    o.x = (vals[t][0] - mean[0]) * rstd[0] * g + be;
    o.y = (vals[t][1] - mean[1]) * rstd[1] * g + be;
    o.z = (vals[t][2] - mean[2]) * rstd[2] * g + be;
    o.w = (vals[t][3] - mean[3]) * rstd[3] * g + be;
    *(float4*)(out + ((size_t)(b * 256 + c)) * 16384 + n0 + wv * 16 + l4 * 4) = o;
  }
}

// ---------------------------------------------------------------------------
extern "C" void kernel_launch(void* const* d_in, const int* in_sizes, int n_in,
                              void* d_out, int out_size, void* d_ws, size_t ws_size,
                              hipStream_t stream) {
  (void)in_sizes; (void)n_in; (void)out_size; (void)ws_size;
  const float* x   = (const float*)d_in[0];
  const float* Wq  = (const float*)d_in[1];
  const float* bq  = (const float*)d_in[2];
  const float* Wk  = (const float*)d_in[3];
  const float* bk  = (const float*)d_in[4];
  const float* Wv  = (const float*)d_in[5];
  const float* bv  = (const float*)d_in[6];
  const float* gK  = (const float*)d_in[7];
  const float* bK  = (const float*)d_in[8];
  const float* gV  = (const float*)d_in[9];
  const float* bV  = (const float*)d_in[10];
  const float* gln = (const float*)d_in[11];
  const float* bln = (const float*)d_in[12];
  float* out = (float*)d_out;

  char* ws = (char*)d_ws;
  float* posT            = (float*)ws;                    // 16,777,216 B
  float* scores          = (float*)(ws + 16777216);       //    262,144 B
  unsigned short* W2     = (unsigned short*)(ws + 17039360); // 1,048,576 B
  float* b2              = (float*)(ws + 18087936);       //      8,192 B

  hipMemsetAsync(scores, 0, 8 * 8 * 32 * 32 * sizeof(float), stream);
  pos_kernel<<<dim3(16384), 256, 0, stream>>>(posT);
  kv_scores_kernel<<<dim3(32, 2, 8), 256, 0, stream>>>(x, posT, Wk, bk, Wv, bv,
                                                       gK, bK, gV, bV, scores);
  w2_kernel<<<dim3(257, 8), 256, 0, stream>>>(Wq, bq, scores, W2, b2);
  out_kernel<<<dim3(256, 8), 256, 0, stream>>>(x, posT, W2, b2, gln, bln, out);
}

// Round 3
// 627.115 us; speedup vs baseline: 1.8375x; 1.8375x over previous
//
#include <hip/hip_runtime.h>

// SelfAttention (Galerkin linear attention), round 3.
// Algebra: qk_in = x + pos ; K = qk_in Wk^T + bk ; V = x Wv^T + bv
//          (per-head LN on K,V) ; S'_h = K_h^T V_h / n
//          W2[he][r] = sum_d Wq[hd][r] S'[d][e] ; b2[he] = sum_d bq[hd] S'[d][e]
//          out = LN(2*(qk_in W2^T + b2)) stored NCHW.
// Workspace-adaptive: batches processed in groups of g (8/4/2/1) so the
// per-group buffers (qkT,xT bf16 [n][k] + W2/scores/b2) fit in ws_size.
// R2 failed replay-validation from ws overflow (85.6 MB, unchecked).

typedef float floatx4 __attribute__((ext_vector_type(4)));
typedef __bf16 bf16x8 __attribute__((ext_vector_type(8)));
typedef unsigned short ushortx8 __attribute__((ext_vector_type(8)));
typedef unsigned short ushort;

static __device__ __forceinline__ ushort f2bf(float f) {
  unsigned int u = __builtin_bit_cast(unsigned int, f);
  u += 0x7FFFu + ((u >> 16) & 1u);  // RNE
  return (ushort)(u >> 16);
}
static __device__ __forceinline__ floatx4 mfma16(bf16x8 a, bf16x8 b, floatx4 c) {
  return __builtin_amdgcn_mfma_f32_16x16x32_bf16(a, b, c, 0, 0, 0);
}
static __device__ __forceinline__ bf16x8 frag(const ushort* p) {
  return *(const bf16x8*)p;  // 16-B aligned by construction -> dwordx4
}

// ---------------------------------------------------------------------------
// Wk, Wv fp32 -> bf16 (plain [oc][256]).
__global__ __launch_bounds__(256) void prep_w(const float* __restrict__ Wk,
                                              const float* __restrict__ Wv,
                                              ushort* __restrict__ Wkbf,
                                              ushort* __restrict__ Wvbf) {
  const int i = (int)blockIdx.x * 256 + (int)threadIdx.x;
  float4 a = ((const float4*)Wk)[i];
  float4 b = ((const float4*)Wv)[i];
  ushort4 ua = {f2bf(a.x), f2bf(a.y), f2bf(a.z), f2bf(a.w)};
  ushort4 ub = {f2bf(b.x), f2bf(b.y), f2bf(b.z), f2bf(b.w)};
  ((ushort4*)Wkbf)[i] = ua;
  ((ushort4*)Wvbf)[i] = ub;
}

// ---------------------------------------------------------------------------
// For batch b0+z: qkT[z][n][k] = bf16(x+pos), xT[z][n][k] = bf16(x).
// LDS transpose of x[k][n] 64x64 chunks; pos synthesized analytically
// (formula HW-validated in R1: kk=k&127, inv=10000^-( (kk>>1)/64 ),
//  arg=coord*inv, kk&1 ? cos : sin).
__global__ __launch_bounds__(256) void prep_qx(const float* __restrict__ x,
                                               ushort* __restrict__ qkT,
                                               ushort* __restrict__ xT, int b0) {
  __shared__ float tile[64 * 68];
  const int t = (int)threadIdx.x;
  const int z = (int)blockIdx.y;
  const int b = b0 + z;
  const int n0 = (int)blockIdx.x * 64;
  const float* xb = x + (size_t)b * 256 * 16384;
  ushort* qb = qkT + (size_t)z * 16384 * 256;
  ushort* xtb = xT + (size_t)z * 16384 * 256;
  for (int kc = 0; kc < 4; ++kc) {
    if (kc) __syncthreads();
    const int nn = (t & 15) * 4;
    const int r0 = t >> 4;
#pragma unroll
    for (int it = 0; it < 4; ++it) {
      const int k = r0 + it * 16;
      const float4 v = *(const float4*)(xb + (size_t)(kc * 64 + k) * 16384 + n0 + nn);
      tile[(nn + 0) * 68 + k] = v.x;
      tile[(nn + 1) * 68 + k] = v.y;
      tile[(nn + 2) * 68 + k] = v.z;
      tile[(nn + 3) * 68 + k] = v.w;
    }
    __syncthreads();
#pragma unroll
    for (int it = 0; it < 2; ++it) {
      const int P = t + it * 256;
      const int r = P >> 3;  // n row 0..63
      const int p = P & 7;   // k chunk of 8
      const int n = n0 + r;
      const int i = n >> 7, j = n & 127;
      ushortx8 uq, ux;
#pragma unroll
      for (int e = 0; e < 8; ++e) {
        const int kg = kc * 64 + p * 8 + e;
        const int kk = kg & 127;
        const float coord = ((kg < 128) ? (float)(i + 1) : (float)(j + 1)) *
                            (6.283185307179586f / (128.0f + 1e-6f));
        const float inv = exp2f(-13.287712379549449f * (float)(kk >> 1) * (1.0f / 64.0f));
        const float arg = coord * inv;
        const float pe = (kk & 1) ? __cosf(arg) : __sinf(arg);
        const float xv = tile[r * 68 + p * 8 + e];
        ux[e] = f2bf(xv);
        uq[e] = f2bf(xv + pe);
      }
      *(ushortx8*)(qb + (size_t)n * 256 + kc * 64 + p * 8) = uq;
      *(ushortx8*)(xtb + (size_t)n * 256 + kc * 64 + p * 8) = ux;
    }
  }
}

// ---------------------------------------------------------------------------
// Per block: (128-n tile, hv, z). Wave w owns head hv*4+w (32 K + 32 V cols).
// K-GEMM from qkT, V-GEMM from xT (direct-global frags, no barriers in k-loop).
// Bias, per-head LN in-wave, K^T/V^T LDS relayout (barriered), S-MFMA, atomics.
#define LDC 72
__global__ __launch_bounds__(256, 2) void kv_scores(
    const ushort* __restrict__ qkT, const ushort* __restrict__ xT,
    const ushort* __restrict__ Wkbf, const ushort* __restrict__ Wvbf,
    const float* __restrict__ bk, const float* __restrict__ bv,
    const float* __restrict__ gK, const float* __restrict__ bKp,
    const float* __restrict__ gV, const float* __restrict__ bVp,
    float* __restrict__ scores) {
  __shared__ ushort KT[128 * LDC];
  __shared__ ushort VT[128 * LDC];
  const int t = (int)threadIdx.x, lane = t & 63, w = t >> 6;
  const int l15 = lane & 15, l4 = lane >> 4;
  const int hv = (int)blockIdx.y, z = (int)blockIdx.z;
  const int n0 = (int)blockIdx.x * 128;
  const ushort* qb = qkT + (size_t)z * 16384 * 256;
  const ushort* xb = xT + (size_t)z * 16384 * 256;
  const int ocb = hv * 128 + w * 32;
  floatx4 acck[2][8] = {};
  floatx4 accv[2][8] = {};
#pragma unroll
  for (int c = 0; c < 8; ++c) {
    const int kb = c * 32 + l4 * 8;
    const bf16x8 bk0 = frag(Wkbf + (ocb + l15) * 256 + kb);
    const bf16x8 bk1 = frag(Wkbf + (ocb + 16 + l15) * 256 + kb);
    const bf16x8 bv0 = frag(Wvbf + (ocb + l15) * 256 + kb);
    const bf16x8 bv1 = frag(Wvbf + (ocb + 16 + l15) * 256 + kb);
#pragma unroll
    for (int m = 0; m < 8; ++m) {
      const bf16x8 aq = frag(qb + (size_t)(n0 + m * 16 + l15) * 256 + kb);
      const bf16x8 ax = frag(xb + (size_t)(n0 + m * 16 + l15) * 256 + kb);
      acck[0][m] = mfma16(aq, bk0, acck[0][m]);
      acck[1][m] = mfma16(aq, bk1, acck[1][m]);
      accv[0][m] = mfma16(ax, bv0, accv[0][m]);
      accv[1][m] = mfma16(ax, bv1, accv[1][m]);
    }
  }
  // bias
  const float bkv[2] = {bk[ocb + l15], bk[ocb + 16 + l15]};
  const float bvv[2] = {bv[ocb + l15], bv[ocb + 16 + l15]};
#pragma unroll
  for (int tt = 0; tt < 2; ++tt)
#pragma unroll
    for (int m = 0; m < 8; ++m)
#pragma unroll
      for (int r = 0; r < 4; ++r) {
        acck[tt][m][r] += bkv[tt];
        accv[tt][m][r] += bvv[tt];
      }
  // per-head LN over 32 channels (tt pair x 16 l15 lanes) per (m,r) row
  const int h = hv * 4 + w;
  const float gk0 = gK[h * 32 + l15], gk1 = gK[h * 32 + 16 + l15];
  const float ok0 = bKp[h * 32 + l15], ok1 = bKp[h * 32 + 16 + l15];
  const float gv0 = gV[h * 32 + l15], gv1 = gV[h * 32 + 16 + l15];
  const float ov0 = bVp[h * 32 + l15], ov1 = bVp[h * 32 + 16 + l15];
#pragma unroll
  for (int m = 0; m < 8; ++m) {
#pragma unroll
    for (int r = 0; r < 4; ++r) {
      {
        const float a0 = acck[0][m][r], a1 = acck[1][m][r];
        float s = a0 + a1, q = a0 * a0 + a1 * a1;
#pragma unroll
        for (int msk = 1; msk < 16; msk <<= 1) {
          s += __shfl_xor(s, msk);
          q += __shfl_xor(q, msk);
        }
        const float mu = s * (1.0f / 32.0f);
        const float rstd = rsqrtf(q * (1.0f / 32.0f) - mu * mu + 1e-5f);
        acck[0][m][r] = (a0 - mu) * rstd * gk0 + ok0;
        acck[1][m][r] = (a1 - mu) * rstd * gk1 + ok1;
      }
      {
        const float a0 = accv[0][m][r], a1 = accv[1][m][r];
        float s = a0 + a1, q = a0 * a0 + a1 * a1;
#pragma unroll
        for (int msk = 1; msk < 16; msk <<= 1) {
          s += __shfl_xor(s, msk);
          q += __shfl_xor(q, msk);
        }
        const float mu = s * (1.0f / 32.0f);
        const float rstd = rsqrtf(q * (1.0f / 32.0f) - mu * mu + 1e-5f);
        accv[0][m][r] = (a0 - mu) * rstd * gv0 + ov0;
        accv[1][m][r] = (a1 - mu) * rstd * gv1 + ov1;
      }
    }
  }
  // K^T/V^T relayout + S-MFMA. Cross-LANE LDS traffic -> barriers required.
  floatx4 sacc[2][2] = {};
#pragma unroll
  for (int half = 0; half < 2; ++half) {
    __syncthreads();
#pragma unroll
    for (int tt = 0; tt < 2; ++tt) {
      const int ch = w * 32 + tt * 16 + l15;
#pragma unroll
      for (int mm = 0; mm < 4; ++mm) {
        const int m = half * 4 + mm;
        const int col = mm * 16 + l4 * 4;
        ushort4 uk = {f2bf(acck[tt][m][0]), f2bf(acck[tt][m][1]),
                      f2bf(acck[tt][m][2]), f2bf(acck[tt][m][3])};
        ushort4 uv = {f2bf(accv[tt][m][0]), f2bf(accv[tt][m][1]),
                      f2bf(accv[tt][m][2]), f2bf(accv[tt][m][3])};
        *(ushort4*)(KT + ch * LDC + col) = uk;
        *(ushort4*)(VT + ch * LDC + col) = uv;
      }
    }
    __syncthreads();
#pragma unroll
    for (int nk = 0; nk < 2; ++nk) {
      const int ko = nk * 32 + l4 * 8;
      const bf16x8 ka0 = *(const bf16x8*)(KT + (w * 32 + l15) * LDC + ko);
      const bf16x8 ka1 = *(const bf16x8*)(KT + (w * 32 + 16 + l15) * LDC + ko);
      const bf16x8 vb0 = *(const bf16x8*)(VT + (w * 32 + l15) * LDC + ko);
      const bf16x8 vb1 = *(const bf16x8*)(VT + (w * 32 + 16 + l15) * LDC + ko);
      sacc[0][0] = mfma16(ka0, vb0, sacc[0][0]);
      sacc[0][1] = mfma16(ka0, vb1, sacc[0][1]);
      sacc[1][0] = mfma16(ka1, vb0, sacc[1][0]);
      sacc[1][1] = mfma16(ka1, vb1, sacc[1][1]);
    }
  }
#pragma unroll
  for (int di = 0; di < 2; ++di)
#pragma unroll
    for (int ej = 0; ej < 2; ++ej)
#pragma unroll
      for (int r = 0; r < 4; ++r) {
        const int d = di * 16 + l4 * 4 + r;
        const int e = ej * 16 + l15;
        atomicAdd(scores + ((size_t)(z * 8 + h) * 32 + d) * 32 + e, sacc[di][ej][r]);
      }
}

// ---------------------------------------------------------------------------
// W2bf[z][he][r] = sum_d Wq[hd][r] S'[d][e] / n ; b2 = bq-fold / n.
__global__ __launch_bounds__(256) void w2_kernel(
    const float* __restrict__ Wq, const float* __restrict__ bq,
    const float* __restrict__ scores, ushort* __restrict__ W2bf,
    float* __restrict__ b2) {
  const int z = (int)blockIdx.y;
  const int row = (int)blockIdx.x;
  const int t = (int)threadIdx.x;
  const float inv_n = 1.0f / 16384.0f;
  const float* sc = scores + (size_t)z * 8192;
  if (row < 256) {
    const int h = row >> 5, e = row & 31;
    float s = 0.0f;
#pragma unroll
    for (int d = 0; d < 32; ++d)
      s += Wq[(h * 32 + d) * 256 + t] * sc[(h * 32 + d) * 32 + e];
    W2bf[(size_t)z * 65536 + row * 256 + t] = f2bf(s * inv_n);
  } else {
    const int h = t >> 5, e = t & 31;
    float s = 0.0f;
#pragma unroll
    for (int d = 0; d < 32; ++d)
      s += bq[h * 32 + d] * sc[(h * 32 + d) * 32 + e];
    b2[z * 256 + t] = s * inv_n;
  }
}

// ---------------------------------------------------------------------------
// out = LN(2*(qk_in W2^T + b2)) stored NCHW. 64-n tile, wave w owns m-tile w.
__global__ __launch_bounds__(256, 2) void out_kernel(
    const ushort* __restrict__ qkT, const ushort* __restrict__ W2bf,
    const float* __restrict__ b2, const float* __restrict__ g_ln,
    const float* __restrict__ b_ln, float* __restrict__ out, int b0) {
  const int t = (int)threadIdx.x, lane = t & 63, w = t >> 6;
  const int l15 = lane & 15, l4 = lane >> 4;
  const int z = (int)blockIdx.y, b = b0 + z;
  const int n0 = (int)blockIdx.x * 64;
  const ushort* qb = qkT + (size_t)z * 16384 * 256;
  const ushort* W2b = W2bf + (size_t)z * 65536;
  floatx4 acc[16] = {};
#pragma unroll
  for (int c = 0; c < 8; ++c) {
    const int kb = c * 32 + l4 * 8;
    const bf16x8 a = frag(qb + (size_t)(n0 + w * 16 + l15) * 256 + kb);
#pragma unroll
    for (int tt = 0; tt < 16; ++tt) {
      const bf16x8 bb = frag(W2b + (tt * 16 + l15) * 256 + kb);
      acc[tt] = mfma16(a, bb, acc[tt]);
    }
  }
  // +b2, double, LN over 256 channels, NCHW store
#pragma unroll
  for (int tt = 0; tt < 16; ++tt) {
    const float b2v = b2[z * 256 + tt * 16 + l15];
#pragma unroll
    for (int r = 0; r < 4; ++r) acc[tt][r] = 2.0f * (acc[tt][r] + b2v);
  }
  float mean[4], rstd[4];
#pragma unroll
  for (int r = 0; r < 4; ++r) {
    float s = 0.0f, q = 0.0f;
#pragma unroll
    for (int tt = 0; tt < 16; ++tt) {
      const float v = acc[tt][r];
      s += v;
      q += v * v;
    }
#pragma unroll
    for (int msk = 1; msk < 16; msk <<= 1) {
      s += __shfl_xor(s, msk);
      q += __shfl_xor(q, msk);
    }
    const float mu = s * (1.0f / 256.0f);
    mean[r] = mu;
    rstd[r] = rsqrtf(q * (1.0f / 256.0f) - mu * mu + 1e-5f);
  }
#pragma unroll
  for (int tt = 0; tt < 16; ++tt) {
    const int c = tt * 16 + l15;
    const float g = g_ln[c], be = b_ln[c];
    float4 o;
    o.x = (acc[tt][0] - mean[0]) * rstd[0] * g + be;
    o.y = (acc[tt][1] - mean[1]) * rstd[1] * g + be;
    o.z = (acc[tt][2] - mean[2]) * rstd[2] * g + be;
    o.w = (acc[tt][3] - mean[3]) * rstd[3] * g + be;
    *(float4*)(out + (size_t)(b * 256 + c) * 16384 + n0 + w * 16 + l4 * 4) = o;
  }
}

// ---------------------------------------------------------------------------
extern "C" void kernel_launch(void* const* d_in, const int* in_sizes, int n_in,
                              void* d_out, int out_size, void* d_ws, size_t ws_size,
                              hipStream_t stream) {
  (void)in_sizes; (void)n_in; (void)out_size;
  const float* x   = (const float*)d_in[0];
  const float* Wq  = (const float*)d_in[1];
  const float* bq  = (const float*)d_in[2];
  const float* Wk  = (const float*)d_in[3];
  const float* bk  = (const float*)d_in[4];
  const float* Wv  = (const float*)d_in[5];
  const float* bv  = (const float*)d_in[6];
  const float* gK  = (const float*)d_in[7];
  const float* bK  = (const float*)d_in[8];
  const float* gV  = (const float*)d_in[9];
  const float* bV  = (const float*)d_in[10];
  const float* gln = (const float*)d_in[11];
  const float* bln = (const float*)d_in[12];
  float* out = (float*)d_out;

  // Per-batch group buffers; pick largest g in {8,4,2,1} that fits ws_size.
  const size_t PB = 16384ULL * 256 * 2;  // 8,388,608 (qkT or xT per batch)
  const size_t W2SZ = 131072, SCSZ = 32768, B2SZ = 1024, WKV = 262144;
  int g = 8;
  while (g > 1 && ws_size < (size_t)g * (2 * PB + W2SZ + SCSZ + B2SZ) + WKV) g >>= 1;
  // g=1 needs 17,204,224 B <= R1's proven-safe 18,096,128 B.

  char* p = (char*)d_ws;
  ushort* qkT   = (ushort*)p; p += (size_t)g * PB;
  ushort* xT    = (ushort*)p; p += (size_t)g * PB;
  ushort* Wkbf  = (ushort*)p; p += 131072;
  ushort* Wvbf  = (ushort*)p; p += 131072;
  ushort* W2bf  = (ushort*)p; p += (size_t)g * W2SZ;
  float*  scores = (float*)p; p += (size_t)g * SCSZ;
  float*  b2    = (float*)p;

  prep_w<<<dim3(64), 256, 0, stream>>>(Wk, Wv, Wkbf, Wvbf);
  for (int b0 = 0; b0 < 8; b0 += g) {
    hipMemsetAsync(scores, 0, (size_t)g * SCSZ, stream);
    prep_qx<<<dim3(256, g), 256, 0, stream>>>(x, qkT, xT, b0);
    kv_scores<<<dim3(128, 2, g), 256, 0, stream>>>(qkT, xT, Wkbf, Wvbf, bk, bv,
                                                   gK, bK, gV, bV, scores);
    w2_kernel<<<dim3(257, g), 256, 0, stream>>>(Wq, bq, scores, W2bf, b2);
    out_kernel<<<dim3(256, g), 256, 0, stream>>>(qkT, W2bf, b2, gln, bln, out, b0);
  }
}